// Round 8
// baseline (62.629 us; speedup 1.0000x reference)
//
#include <hip/hip_runtime.h>

// DynamicKoopmanOperator — R8: fused kernel + LDS-staged W (global_load_lds).
// Diagnosis: store phase ~43-45us (~6.2 TB/s, near fill's 7.0 ceiling); MLP
// phase ~16us and INVARIANT across 3 different structures -> W-load latency
// chain (8-deep unroll never achieves 8 outstanding; SMEM x-loads force
// lgkmcnt(0) drains). Fix: double-buffered 32-row W chunks staged via
// global_load_lds width=16 (bulk-issued, vmcnt drained once per chunk under
// the previous chunk's FMAs). W reads from LDS stride-1 (2-way = free);
// x/h as uniform ds_read_b128 broadcasts (DS is in-order).

#define DT_CONST 0.01f

typedef float f32x4 __attribute__((ext_vector_type(4)));

constexpr int KDIM   = 256;
constexpr int AROWS  = 4;              // batch rows per block -> 256 blocks
constexpr int CROWS  = 32;             // k-rows per staged W chunk (32 KiB)
constexpr int NCHUNK = KDIM / CROWS;   // 8
constexpr int NW     = 8;              // waves per block (512 threads)
constexpr int RPW    = CROWS / NW;     // 4 staged rows per wave per chunk

// one k-row of W (256 floats = 1 KiB) -> LDS. Per-lane global src, wave-
// uniform LDS base; HW scatters lane l to base + l*16 (linear row layout).
__device__ __forceinline__ void stage_row(const float* gsrc, float* ldst, int lane)
{
    __builtin_amdgcn_global_load_lds(
        (const __attribute__((address_space(1))) void*)(gsrc + lane * 4),
        (__attribute__((address_space(3))) void*)ldst,
        16, 0, 0);
}

__device__ __forceinline__ void stage_chunk(const float* W, int c, float* buf,
                                            int wave, int lane)
{
#pragma unroll
    for (int i = 0; i < RPW; ++i) {
        const int row = wave * RPW + i;
        stage_row(W + (size_t)(c * CROWS + row) * KDIM, buf + row * KDIM, lane);
    }
}

// ---------------- fused kernel ----------------------------------------------
__global__ __launch_bounds__(512) void koopman_fused(
    const float* __restrict__ x,  const float* __restrict__ W1,
    const float* __restrict__ b1, const float* __restrict__ W2,
    const float* __restrict__ b2, float* __restrict__ out, int T)
{
    __shared__ alignas(16) float Wb[2][CROWS * KDIM];   // 64 KiB, dbuf W chunks
    __shared__ alignas(16) float xs[AROWS][KDIM];       // 4 KiB x rows
    __shared__ alignas(16) float hs[AROWS][KDIM];       // 4 KiB hidden
    __shared__ alignas(16) float coef[AROWS][KDIM];     // 4 KiB eig*dt
    __shared__ alignas(16) float part[2][AROWS][KDIM];  // 8 KiB ksplit partials

    const int tid  = threadIdx.x;
    const int j    = tid & (KDIM - 1);   // output column 0..255
    const int kh   = tid >> 8;           // k-half 0/1 (wave-uniform)
    const int wave = tid >> 6;           // 0..7
    const int lane = tid & 63;
    const int b0   = blockIdx.x * AROWS;

    // stage x rows (plain LDS writes) + issue W1 chunk 0
    for (int i = tid; i < AROWS * KDIM; i += 512)
        xs[i >> 8][i & (KDIM - 1)] = x[(size_t)b0 * KDIM + i];
    stage_chunk(W1, 0, Wb[0], wave, lane);
    __syncthreads();                      // drains ds_write + vmcnt(0)

    float acc[AROWS];

    // ---- GEMM 1: h = tanh(x @ W1 + b1), k split kh*16..+16 of each chunk ----
#pragma unroll
    for (int r = 0; r < AROWS; ++r) acc[r] = 0.f;
    for (int c = 0; c < NCHUNK; ++c) {
        const int cur = c & 1;
        if (c + 1 < NCHUNK)
            stage_chunk(W1, c + 1, Wb[cur ^ 1], wave, lane);  // issue early
#pragma unroll
        for (int g = 0; g < 4; ++g) {
            const int kl = kh * 16 + g * 4;       // local k-row in chunk
            const int kg = c * CROWS + kl;        // global k
            f32x4 xv[AROWS];
#pragma unroll
            for (int r = 0; r < AROWS; ++r)       // uniform b128 broadcast
                xv[r] = *reinterpret_cast<const f32x4*>(&xs[r][kg]);
#pragma unroll
            for (int i = 0; i < 4; ++i) {
                const float wk = Wb[cur][(kl + i) * KDIM + j];  // stride-1, free
#pragma unroll
                for (int r = 0; r < AROWS; ++r)
                    acc[r] = fmaf(xv[r][i], wk, acc[r]);
            }
        }
        __syncthreads();                  // vmcnt(0): next chunk landed
    }
#pragma unroll
    for (int r = 0; r < AROWS; ++r) part[kh][r][j] = acc[r];
    __syncthreads();
    if (kh == 0) {
#pragma unroll
        for (int r = 0; r < AROWS; ++r)
            hs[r][j] = tanhf(part[0][r][j] + part[1][r][j] + b1[j]);
    }
    stage_chunk(W2, 0, Wb[0], wave, lane);  // W2 chunk 0 under the tanh
    __syncthreads();

    // ---- GEMM 2: eigs = h @ W2 + b2 ----
#pragma unroll
    for (int r = 0; r < AROWS; ++r) acc[r] = 0.f;
    for (int c = 0; c < NCHUNK; ++c) {
        const int cur = c & 1;
        if (c + 1 < NCHUNK)
            stage_chunk(W2, c + 1, Wb[cur ^ 1], wave, lane);
#pragma unroll
        for (int g = 0; g < 4; ++g) {
            const int kl = kh * 16 + g * 4;
            const int kg = c * CROWS + kl;
            f32x4 hv[AROWS];
#pragma unroll
            for (int r = 0; r < AROWS; ++r)
                hv[r] = *reinterpret_cast<const f32x4*>(&hs[r][kg]);
#pragma unroll
            for (int i = 0; i < 4; ++i) {
                const float wk = Wb[cur][(kl + i) * KDIM + j];
#pragma unroll
                for (int r = 0; r < AROWS; ++r)
                    acc[r] = fmaf(hv[r][i], wk, acc[r]);
            }
        }
        __syncthreads();
    }
#pragma unroll
    for (int r = 0; r < AROWS; ++r) part[kh][r][j] = acc[r];
    __syncthreads();
    if (kh == 0) {
#pragma unroll
        for (int r = 0; r < AROWS; ++r)
            coef[r][j] = (part[0][r][j] + part[1][r][j] + b2[j]) * DT_CONST;
    }
    __syncthreads();

    // ---- Phase 2: rollout. wave -> (row, T-half); closed-form seed ----
    const int r    = wave & (AROWS - 1);    // row within block
    const int tseg = wave >> 2;             // 0/1
    const int b    = b0 + r;
    const int tlen = (T + 1) >> 1;          // 128
    const int t0   = tseg * tlen;

    const f32x4 c  = *reinterpret_cast<const f32x4*>(&coef[r][lane * 4]);
    const f32x4 xv = *reinterpret_cast<const f32x4*>(&xs[r][lane * 4]);
    // c = (mu0*dt, om0*dt, mu1*dt, om1*dt)

    const float tf = (float)t0;
    float s, co, e;
    e = expf(c.x * tf); sincosf(c.y * tf, &s, &co);
    float z0 = e * (co * xv.x - s * xv.y);
    float z1 = e * (s * xv.x + co * xv.y);
    e = expf(c.z * tf); sincosf(c.w * tf, &s, &co);
    float z2 = e * (co * xv.z - s * xv.w);
    float z3 = e * (s * xv.z + co * xv.w);

    e = expf(c.x); sincosf(c.y, &s, &co);
    const float a0 = e * co, g0 = e * s;
    e = expf(c.z); sincosf(c.w, &s, &co);
    const float a1 = e * co, g1 = e * s;

    f32x4* orow = reinterpret_cast<f32x4*>(out + ((size_t)b * T + t0) * KDIM) + lane;
    const int nt = ((t0 + tlen < T) ? tlen : (T - t0));
#pragma unroll 4
    for (int t = 0; t < nt; ++t) {
        float n0 = a0 * z0 - g0 * z1;
        float n1 = g0 * z0 + a0 * z1;
        float n2 = a1 * z2 - g1 * z3;
        float n3 = g1 * z2 + a1 * z3;
        f32x4 v = { n0, n1, n2, n3 };
        *orow = v;                           // plain store, through L2
        orow += KDIM / 4;                    // next timestep, 1 KiB row/wave
        z0 = n0; z1 = n1; z2 = n2; z3 = n3;
    }
}

// ---------------- launcher ---------------------------------------------------
extern "C" void kernel_launch(void* const* d_in, const int* in_sizes, int n_in,
                              void* d_out, int out_size, void* d_ws, size_t ws_size,
                              hipStream_t stream) {
    const float* x  = (const float*)d_in[0];
    const float* W1 = (const float*)d_in[1];
    const float* b1 = (const float*)d_in[2];
    const float* W2 = (const float*)d_in[3];
    const float* b2 = (const float*)d_in[4];

    const int Kd = in_sizes[2];                 // 256
    const int Bb = in_sizes[0] / Kd;            // 1024
    const int T  = out_size / (Bb * Kd);        // 256

    float* out = (float*)d_out;

    koopman_fused<<<Bb / AROWS, 512, 0, stream>>>(x, W1, b1, W2, b2, out, T);
}

// Round 9
// 52.423 us; speedup vs baseline: 1.1947x; 1.1947x over previous
//
#include <hip/hip_runtime.h>

// DynamicKoopmanOperator — R9: fused; MLP restructured for 16B/instr W delivery.
// R8 lesson: MLP (~16.5us, invariant across 4 structures) was operand-ISSUE
// bound: W delivered 4B/instr (ds_read_b32 / b32 loads) -> ~36k LDS-pipe
// cycles/CU. Now: thread owns 4 cols x 4 rows; W via global_load_dwordx4
// (VMEM pipe, 1KB/wave/instr, ~9k cyc/CU); x via uniform ds_read_b128
// broadcast (DS pipe, ~6k cyc/CU); FMA ~4k cyc/SIMD. Pipes overlap -> ~5us.
// Rollout phase (42us @ 6.36 TB/s, 90% of fill's 7.08 ceiling) unchanged.

#define DT_CONST 0.01f

typedef float f32x4 __attribute__((ext_vector_type(4)));

constexpr int KDIM   = 256;
constexpr int AROWS  = 4;               // batch rows per block -> 256 blocks
constexpr int KSPLIT = 8;               // k-slices (= wave id)
constexpr int KSLICE = KDIM / KSPLIT;   // 32 k's per slice

// ---------------- fused kernel ----------------------------------------------
__global__ __launch_bounds__(512) void koopman_fused(
    const float* __restrict__ x,  const float* __restrict__ W1,
    const float* __restrict__ b1, const float* __restrict__ W2,
    const float* __restrict__ b2, float* __restrict__ out, int T)
{
    __shared__ alignas(16) float xs[AROWS][KDIM];              // 4 KiB
    __shared__ alignas(16) float hs[AROWS][KDIM];              // 4 KiB
    __shared__ alignas(16) float coef[AROWS][KDIM];            // 4 KiB
    __shared__ alignas(16) float part[KSPLIT][AROWS][KDIM];    // 32 KiB

    const int tid = threadIdx.x;
    const int jg  = tid & 63;           // column group: cols [jg*4, jg*4+4)
    const int ks  = tid >> 6;           // k-slice 0..7 (wave-uniform)
    const int b0  = blockIdx.x * AROWS;

    // stage x rows (vectorized, 256 f32x4)
    {
        const f32x4* xg = reinterpret_cast<const f32x4*>(x + (size_t)b0 * KDIM);
        f32x4* xl = reinterpret_cast<f32x4*>(&xs[0][0]);
        for (int i = tid; i < AROWS * KDIM / 4; i += 512) xl[i] = xg[i];
    }
    __syncthreads();

    f32x4 acc[AROWS];

    // ---- GEMM 1: h = tanh(x @ W1 + b1) ----
    {
#pragma unroll
        for (int r = 0; r < AROWS; ++r) acc[r] = (f32x4){0.f, 0.f, 0.f, 0.f};
        const float* wbase = W1 + (size_t)ks * KSLICE * KDIM + jg * 4;
#pragma unroll 2
        for (int k4 = 0; k4 < KSLICE / 4; ++k4) {
            f32x4 wv[4];
#pragma unroll
            for (int i = 0; i < 4; ++i)      // 4x global dwordx4, coalesced
                wv[i] = *reinterpret_cast<const f32x4*>(wbase + (size_t)(k4 * 4 + i) * KDIM);
            f32x4 xv[AROWS];
#pragma unroll
            for (int r = 0; r < AROWS; ++r)  // uniform b128 broadcast
                xv[r] = *reinterpret_cast<const f32x4*>(&xs[r][ks * KSLICE + k4 * 4]);
#pragma unroll
            for (int i = 0; i < 4; ++i)
#pragma unroll
                for (int r = 0; r < AROWS; ++r)
                    acc[r] += wv[i] * xv[r][i];      // vec FMA (contract=fast)
        }
#pragma unroll
        for (int r = 0; r < AROWS; ++r)
            *reinterpret_cast<f32x4*>(&part[ks][r][jg * 4]) = acc[r];
    }
    __syncthreads();
    // reduce ksplit partials + bias + tanh -> hs
    for (int idx = tid; idx < AROWS * KDIM; idx += 512) {
        const int r = idx >> 8, j = idx & (KDIM - 1);
        float ssum = b1[j];
#pragma unroll
        for (int s = 0; s < KSPLIT; ++s) ssum += part[s][r][j];
        hs[r][j] = tanhf(ssum);
    }
    __syncthreads();

    // ---- GEMM 2: eigs = h @ W2 + b2 ----
    {
#pragma unroll
        for (int r = 0; r < AROWS; ++r) acc[r] = (f32x4){0.f, 0.f, 0.f, 0.f};
        const float* wbase = W2 + (size_t)ks * KSLICE * KDIM + jg * 4;
#pragma unroll 2
        for (int k4 = 0; k4 < KSLICE / 4; ++k4) {
            f32x4 wv[4];
#pragma unroll
            for (int i = 0; i < 4; ++i)
                wv[i] = *reinterpret_cast<const f32x4*>(wbase + (size_t)(k4 * 4 + i) * KDIM);
            f32x4 hv[AROWS];
#pragma unroll
            for (int r = 0; r < AROWS; ++r)
                hv[r] = *reinterpret_cast<const f32x4*>(&hs[r][ks * KSLICE + k4 * 4]);
#pragma unroll
            for (int i = 0; i < 4; ++i)
#pragma unroll
                for (int r = 0; r < AROWS; ++r)
                    acc[r] += wv[i] * hv[r][i];
        }
#pragma unroll
        for (int r = 0; r < AROWS; ++r)
            *reinterpret_cast<f32x4*>(&part[ks][r][jg * 4]) = acc[r];
    }
    __syncthreads();
    // reduce + bias, pre-scale by dt -> coef
    for (int idx = tid; idx < AROWS * KDIM; idx += 512) {
        const int r = idx >> 8, j = idx & (KDIM - 1);
        float ssum = b2[j];
#pragma unroll
        for (int s = 0; s < KSPLIT; ++s) ssum += part[s][r][j];
        coef[r][j] = ssum * DT_CONST;
    }
    __syncthreads();

    // ---- Phase 2: rollout. wave -> (row, T-half); closed-form seed ----
    const int wave = tid >> 6;
    const int lane = tid & 63;              // lane = 2 pairs (4 elems)
    const int r    = wave & (AROWS - 1);    // row within block
    const int tseg = wave >> 2;             // 0/1
    const int b    = b0 + r;
    const int tlen = (T + 1) >> 1;          // 128
    const int t0   = tseg * tlen;

    const f32x4 c  = *reinterpret_cast<const f32x4*>(&coef[r][lane * 4]);
    const f32x4 xv = *reinterpret_cast<const f32x4*>(&xs[r][lane * 4]);
    // c = (mu0*dt, om0*dt, mu1*dt, om1*dt)

    const float tf = (float)t0;
    float s, co, e;
    e = expf(c.x * tf); sincosf(c.y * tf, &s, &co);
    float z0 = e * (co * xv.x - s * xv.y);
    float z1 = e * (s * xv.x + co * xv.y);
    e = expf(c.z * tf); sincosf(c.w * tf, &s, &co);
    float z2 = e * (co * xv.z - s * xv.w);
    float z3 = e * (s * xv.z + co * xv.w);

    e = expf(c.x); sincosf(c.y, &s, &co);
    const float a0 = e * co, g0 = e * s;
    e = expf(c.z); sincosf(c.w, &s, &co);
    const float a1 = e * co, g1 = e * s;

    f32x4* orow = reinterpret_cast<f32x4*>(out + ((size_t)b * T + t0) * KDIM) + lane;
    const int nt = ((t0 + tlen < T) ? tlen : (T - t0));
#pragma unroll 4
    for (int t = 0; t < nt; ++t) {
        float n0 = a0 * z0 - g0 * z1;
        float n1 = g0 * z0 + a0 * z1;
        float n2 = a1 * z2 - g1 * z3;
        float n3 = g1 * z2 + a1 * z3;
        f32x4 v = { n0, n1, n2, n3 };
        *orow = v;                           // plain store, through L2
        orow += KDIM / 4;                    // next timestep, 1 KiB row/wave
        z0 = n0; z1 = n1; z2 = n2; z3 = n3;
    }
}

// ---------------- launcher ---------------------------------------------------
extern "C" void kernel_launch(void* const* d_in, const int* in_sizes, int n_in,
                              void* d_out, int out_size, void* d_ws, size_t ws_size,
                              hipStream_t stream) {
    const float* x  = (const float*)d_in[0];
    const float* W1 = (const float*)d_in[1];
    const float* b1 = (const float*)d_in[2];
    const float* W2 = (const float*)d_in[3];
    const float* b2 = (const float*)d_in[4];

    const int Kd = in_sizes[2];                 // 256
    const int Bb = in_sizes[0] / Kd;            // 1024
    const int T  = out_size / (Bb * Kd);        // 256

    float* out = (float*)d_out;

    koopman_fused<<<Bb / AROWS, 512, 0, stream>>>(x, W1, b1, W2, b2, out, T);
}